// Round 3
// baseline (29.586 us; speedup 1.0000x reference)
//
#include <hip/hip_runtime.h>
#include <hip/hip_bf16.h>

#define D_MODEL 4096
#define NN      4403      // selected neurons
#define NB      64        // batch
#define BN      64        // neurons per block (4 waves x 16)
#define KCH     512       // K per block (one LDS X panel)
#define KSPLIT  (D_MODEL / KCH)   // 8
#define LDX     520       // shorts per X row: 65 16B-slots (odd mod 8 -> uniform bank residues)
#define OUT_ELEMS (NB * NN)       // 281792
#define WS_NEEDED ((size_t)KSPLIT * OUT_ELEMS * 4)

using f32x4  = __attribute__((ext_vector_type(4))) float;
using bf16x8 = __attribute__((ext_vector_type(8))) short;
using u16x8  = __attribute__((ext_vector_type(8))) unsigned short;

__device__ __forceinline__ unsigned short f2bf(float f) {
    __hip_bfloat16 h = __float2bfloat16(f);     // RNE; compiler can fuse to v_cvt_pk_bf16_f32
    return __builtin_bit_cast(unsigned short, h);
}

__device__ __forceinline__ u16x8 pack8(f32x4 a, f32x4 b) {
    u16x8 v;
    v[0] = f2bf(a[0]); v[1] = f2bf(a[1]); v[2] = f2bf(a[2]); v[3] = f2bf(a[3]);
    v[4] = f2bf(b[0]); v[5] = f2bf(b[1]); v[6] = f2bf(b[2]); v[7] = f2bf(b[3]);
    return v;
}

template <bool ATOMIC>
__global__ __launch_bounds__(256, 2)
void gather_gemm_bf16(const float* __restrict__ X,
                      const float* __restrict__ W,
                      const int*   __restrict__ idx,
                      float* __restrict__ out)   // partial base (or out if ATOMIC)
{
    __shared__ __align__(16) unsigned short Xs[64 * LDX];   // 66.5 KB

    const int tid   = threadIdx.x;
    const int wave  = tid >> 6;
    const int lane  = tid & 63;
    const int n0    = blockIdx.x * BN;
    const int kbase = blockIdx.y * KCH;

    const int fr = lane & 15;          // fragment row (neuron within wave tile / batch within m-tile)
    const int g  = lane >> 4;          // k-group
    const int fk = g * 8;

    // ---- per-lane W gather pointer (B-operand streams straight from global) ----
    const int n    = n0 + wave * 16 + fr;
    const int wrow = (n < NN) ? idx[n] : 0;        // clamp: lanes discarded in epilogue
    const float* wp = W + (size_t)wrow * D_MODEL + kbase + fk;

    // issue W group 0 early — overlaps X staging below
    f32x4 wa[4][2];
#pragma unroll
    for (int kk = 0; kk < 4; ++kk) {
        wa[kk][0] = *(const f32x4*)(wp + kk * 32);
        wa[kk][1] = *(const f32x4*)(wp + kk * 32 + 4);
    }

    // ---- X staging: 64 rows x 512 f32 -> bf16 LDS panel, one barrier ----
    {
        const int row8 = tid >> 5;     // 0..7
        const int colf = tid & 31;     // x16 floats
#pragma unroll
        for (int c = 0; c < 8; ++c) {
            const int row = c * 8 + row8;
            const float* xp = X + (size_t)row * D_MODEL + kbase + colf * 16;
            f32x4 a0 = *(const f32x4*)(xp + 0);
            f32x4 a1 = *(const f32x4*)(xp + 4);
            f32x4 a2 = *(const f32x4*)(xp + 8);
            f32x4 a3 = *(const f32x4*)(xp + 12);
            *(u16x8*)&Xs[row * LDX + colf * 16 + 0] = pack8(a0, a1);
            *(u16x8*)&Xs[row * LDX + colf * 16 + 8] = pack8(a2, a3);
        }
    }
    __syncthreads();

    f32x4 acc[4];
#pragma unroll
    for (int m = 0; m < 4; ++m) acc[m] = (f32x4){0.f, 0.f, 0.f, 0.f};

    // ---- K loop: 4 groups x 4 MFMA-steps, W register-double-buffered, no barriers ----
    f32x4 wn[4][2];
#pragma unroll
    for (int grp = 0; grp < 4; ++grp) {
        if (grp < 3) {
#pragma unroll
            for (int kk = 0; kk < 4; ++kk) {
                wn[kk][0] = *(const f32x4*)(wp + (grp + 1) * 128 + kk * 32);
                wn[kk][1] = *(const f32x4*)(wp + (grp + 1) * 128 + kk * 32 + 4);
            }
        }
#pragma unroll
        for (int kk = 0; kk < 4; ++kk) {
            bf16x8 bfrag = __builtin_bit_cast(bf16x8, pack8(wa[kk][0], wa[kk][1]));
#pragma unroll
            for (int m = 0; m < 4; ++m) {
                bf16x8 afrag = *(const bf16x8*)&Xs[(m * 16 + fr) * LDX + (grp * 4 + kk) * 32 + fk];
                acc[m] = __builtin_amdgcn_mfma_f32_16x16x32_bf16(afrag, bfrag, acc[m], 0, 0, 0);
            }
        }
        if (grp < 3) {
#pragma unroll
            for (int kk = 0; kk < 4; ++kk) { wa[kk][0] = wn[kk][0]; wa[kk][1] = wn[kk][1]; }
        }
    }

    // ---- epilogue: C/D col = lane&15 (neuron), row = (lane>>4)*4 + reg (batch) ----
    const int ncol = n0 + wave * 16 + fr;
    if (ncol < NN) {
        float* base = ATOMIC ? out : out + (size_t)blockIdx.y * OUT_ELEMS;
#pragma unroll
        for (int m = 0; m < 4; ++m) {
            int brow = m * 16 + g * 4;
#pragma unroll
            for (int r = 0; r < 4; ++r) {
                if (ATOMIC)
                    atomicAdd(&base[(size_t)(brow + r) * NN + ncol], acc[m][r]);
                else
                    base[(size_t)(brow + r) * NN + ncol] = acc[m][r];
            }
        }
    }
}

// out[i] = sum_s partial[s][i]   (fully coalesced float4 both ways)
__global__ __launch_bounds__(256)
void reduce_splitk(const float* __restrict__ p, float* __restrict__ out) {
    const int i = blockIdx.x * 256 + threadIdx.x;        // float4 index
    const int n4 = OUT_ELEMS / 4;                        // 70448
    if (i >= n4) return;
    const f32x4* p4 = (const f32x4*)p;
    f32x4 a = p4[i];
#pragma unroll
    for (int s = 1; s < KSPLIT; ++s) a += p4[(size_t)s * n4 + i];
    ((f32x4*)out)[i] = a;
}

extern "C" void kernel_launch(void* const* d_in, const int* in_sizes, int n_in,
                              void* d_out, int out_size, void* d_ws, size_t ws_size,
                              hipStream_t stream) {
    const float* X   = (const float*)d_in[0];   // [64,1,4096] f32
    const float* W   = (const float*)d_in[1];   // [11008,4096] f32
    const int*   idx = (const int*)d_in[2];     // [4403] i32
    float* out = (float*)d_out;                 // [64,1,4403] f32

    dim3 grid((NN + BN - 1) / BN, KSPLIT, 1);   // 69 x 8 = 552 blocks (~2/CU)

    if (ws_size >= WS_NEEDED) {
        float* partial = (float*)d_ws;
        gather_gemm_bf16<false><<<grid, 256, 0, stream>>>(X, W, idx, partial);
        int n4 = OUT_ELEMS / 4;
        reduce_splitk<<<(n4 + 255) / 256, 256, 0, stream>>>(partial, out);
    } else {
        hipMemsetAsync(d_out, 0, (size_t)out_size * sizeof(float), stream);
        gather_gemm_bf16<true><<<grid, 256, 0, stream>>>(X, W, idx, out);
    }
}